// Round 4
// baseline (214.910 us; speedup 1.0000x reference)
//
#include <hip/hip_runtime.h>

// B=2, L=2048, DIM=1024, H=16, HD=64; scale folded into Q: 0.125*log2e; mask: -60*log2e
#define LL 2048
#define NHEADS 16
#define HDIM 64
#define QSCALE 0.18033688011112042f   // 0.125 * log2(e)
#define MASKC1 -86.56170245333780f    // -60 * log2(e)

typedef __attribute__((ext_vector_type(8))) __bf16 bf16x8;
typedef __attribute__((ext_vector_type(4))) float f32x4;

__device__ __forceinline__ unsigned short f2bf(float f) {
  unsigned int u = __builtin_bit_cast(unsigned int, f);
  u += 0x7fffu + ((u >> 16) & 1u);   // RNE
  return (unsigned short)(u >> 16);
}

__device__ __forceinline__ bf16x8 ld_frag(const unsigned short* p) {
  return *reinterpret_cast<const bf16x8*>(p);
}

// async global->LDS, 16B per lane; LDS dest = wave-uniform base + lane*16
__device__ __forceinline__ void async_cp16(const unsigned short* g, unsigned short* l) {
  __builtin_amdgcn_global_load_lds(
      (const __attribute__((address_space(1))) unsigned int*)(unsigned long long)(g),
      (__attribute__((address_space(3))) unsigned int*)(unsigned int)(unsigned long long)(l),
      16, 0, 0);
}

// ---------------- fused prep: x fp32->bf16 (blocks 0..4095) + W transpose (4096..4863) ----------
__global__ __launch_bounds__(256) void prep_kernel(
    const float* __restrict__ x, const float* __restrict__ Wq, const float* __restrict__ Wk,
    const float* __restrict__ Wv, unsigned short* __restrict__ xb,
    unsigned short* __restrict__ WtAll) {
  __shared__ float t[64][65];
  int blk = blockIdx.x;
  if (blk < 4096) {
    int i = (blk * 256 + threadIdx.x) * 4;
    float4 v = *reinterpret_cast<const float4*>(x + i);
    ushort4 o;
    o.x = f2bf(v.x); o.y = f2bf(v.y); o.z = f2bf(v.z); o.w = f2bf(v.w);
    *reinterpret_cast<ushort4*>(xb + i) = o;
  } else {
    int idx = blk - 4096;
    int z = idx >> 8; idx &= 255;
    const float* W = (z == 0) ? Wq : (z == 1) ? Wk : Wv;
    unsigned short* dst = WtAll + (size_t)z * 1024 * 1024;
    int n0 = (idx & 15) * 64, k0 = (idx >> 4) * 64;
    int tx = threadIdx.x & 63, ty = threadIdx.x >> 6;
#pragma unroll
    for (int p = 0; p < 16; ++p) {
      int kr = p * 4 + ty;
      t[kr][tx] = W[(size_t)(k0 + kr) * 1024 + n0 + tx];
    }
    __syncthreads();
#pragma unroll
    for (int p = 0; p < 16; ++p) {
      int nr = p * 4 + ty;
      dst[(size_t)(n0 + nr) * 1024 + k0 + tx] = f2bf(t[tx][nr]);
    }
  }
}

// ---------------- prep: em = bf16(exp2(mask*MASKC1)), key-permuted pos=4c+q ----------------
__global__ __launch_bounds__(256) void em_prep_kernel(const float* __restrict__ mask,
                                                      unsigned short* __restrict__ em) {
  int row = blockIdx.y;
  int t = blockIdx.x * 256 + threadIdx.x;
  int kb = t >> 4, c = t & 15;
  const float* src = mask + (size_t)row * LL + kb * 64 + c;
  ushort4 o;
  o.x = f2bf(__builtin_amdgcn_exp2f(src[0]  * MASKC1));
  o.y = f2bf(__builtin_amdgcn_exp2f(src[16] * MASKC1));
  o.z = f2bf(__builtin_amdgcn_exp2f(src[32] * MASKC1));
  o.w = f2bf(__builtin_amdgcn_exp2f(src[48] * MASKC1));
  *reinterpret_cast<ushort4*>(em + (size_t)row * LL + kb * 64 + 4 * c) = o;
}

// ---------------- QKV projection GEMM (async staging, swizzled rows) ----------------
// grid (8, 32, 3). z==0: Q bf16 [bh][l][d] * QSCALE; z==1: K; z==2: V^T [bh][d][l], pos-permuted.
__global__ __launch_bounds__(256) void qkv_gemm_kernel(
    const unsigned short* __restrict__ xb, const unsigned short* __restrict__ WtAll,
    const float* __restrict__ bq, const float* __restrict__ bk, const float* __restrict__ bv,
    unsigned short* __restrict__ qkv) {
  const int z = blockIdx.z;
  const unsigned short* Wt = WtAll + (size_t)z * 1024 * 1024;
  const float* bias = (z == 0) ? bq : (z == 1) ? bk : bv;
  unsigned short* outb = qkv + (size_t)z * 4194304;

  __shared__ __align__(16) unsigned short smem[16384];  // As 8192, Bs 8192 (stride 64, swizzled)
  unsigned short* As = smem;
  unsigned short* Bs = smem + 8192;

  const int tid = threadIdx.x;
  const int w = tid >> 6, lane = tid & 63, g = lane >> 4, cc = lane & 15;
  const int wm = w >> 1, wn = w & 1;
  const int m0 = blockIdx.y * 128, n0 = blockIdx.x * 128;
  const int srow = lane >> 3;                 // row within seg
  const int gc = ((lane & 7) - srow) & 7;     // swizzle: LDS slot s holds chunk (s - row)&7
  const unsigned short* ga = xb + (size_t)(m0 + w * 32 + srow) * 1024 + gc * 8;
  const unsigned short* gb = Wt + (size_t)(n0 + w * 32 + srow) * 1024 + gc * 8;
  unsigned short* la = As + w * 2048;
  unsigned short* lb = Bs + w * 2048;

  f32x4 acc[4][4];
#pragma unroll
  for (int i = 0; i < 4; ++i)
#pragma unroll
    for (int j = 0; j < 4; ++j) acc[i][j] = (f32x4)0.0f;

  for (int kk = 0; kk < 1024; kk += 64) {
    __syncthreads();
#pragma unroll
    for (int i = 0; i < 4; ++i) {
      async_cp16(ga + i * 8192 + kk, la + i * 512);
      async_cp16(gb + i * 8192 + kk, lb + i * 512);
    }
    __syncthreads();
    bf16x8 af[4][2], bfr[4][2];
#pragma unroll
    for (int mt = 0; mt < 4; ++mt)
#pragma unroll
      for (int ks = 0; ks < 2; ++ks)
        af[mt][ks] = ld_frag(&As[(wm * 64 + mt * 16 + cc) * 64 + ((4 * ks + g + cc) & 7) * 8]);
#pragma unroll
    for (int nt = 0; nt < 4; ++nt)
#pragma unroll
      for (int ks = 0; ks < 2; ++ks)
        bfr[nt][ks] = ld_frag(&Bs[(wn * 64 + nt * 16 + cc) * 64 + ((4 * ks + g + cc) & 7) * 8]);
#pragma unroll
    for (int mt = 0; mt < 4; ++mt)
#pragma unroll
      for (int nt = 0; nt < 4; ++nt)
#pragma unroll
        for (int ks = 0; ks < 2; ++ks)
          acc[mt][nt] = __builtin_amdgcn_mfma_f32_16x16x32_bf16(af[mt][ks], bfr[nt][ks],
                                                                acc[mt][nt], 0, 0, 0);
  }

  if (z != 2) {
    const float sc = (z == 0) ? QSCALE : 1.0f;
#pragma unroll
    for (int nt = 0; nt < 4; ++nt) {
      int n = n0 + wn * 64 + nt * 16 + cc;
      float bval = bias[n];
      int h = n >> 6, d = n & 63;
#pragma unroll
      for (int mt = 0; mt < 4; ++mt) {
#pragma unroll
        for (int r = 0; r < 4; ++r) {
          int m = m0 + wm * 64 + mt * 16 + g * 4 + r;
          int b = m >> 11, l = m & 2047;
          outb[(((size_t)(b * NHEADS + h) * LL) + l) * HDIM + d] =
              f2bf((acc[mt][nt][r] + bval) * sc);
        }
      }
    }
  } else {
    // V^T epilogue with key permutation pos = 4c + q: local = mt*16+g*4+r -> pos = 16g+4r+mt
    __syncthreads();
#pragma unroll
    for (int nt = 0; nt < 4; ++nt) {
      int nr = wn * 64 + nt * 16 + cc;
      float bval = bias[n0 + nr];
#pragma unroll
      for (int mt = 0; mt < 4; ++mt)
#pragma unroll
        for (int r = 0; r < 4; ++r)
          smem[nr * 128 + wm * 64 + 16 * g + 4 * r + mt] = f2bf(acc[mt][nt][r] + bval);
    }
    __syncthreads();
    int row = tid >> 1, half = tid & 1;
    int n = n0 + row, hh = n >> 6, dd = n & 63;
    int bb = m0 >> 11, l0 = (m0 & 2047) + half * 64;
    unsigned short* dst = outb + ((size_t)(bb * NHEADS + hh) * HDIM + dd) * LL + l0;
#pragma unroll
    for (int i = 0; i < 8; ++i)
      *reinterpret_cast<uint4*>(dst + i * 8) =
          *reinterpret_cast<const uint4*>(&smem[row * 128 + half * 64 + i * 8]);
  }
}

// ---------------- flash attention ----------------
// grid (32, 32): 64-row q-tiles. LDS = exactly 40KB -> 4 blocks/CU (16 waves/CU).
// Ping-pong K/V via global_load_lds; Ps unpadded with 16B-chunk rotation swizzle.
__global__ __launch_bounds__(256, 4) void flash_kernel(
    const unsigned short* __restrict__ Qb, const unsigned short* __restrict__ Kb,
    const unsigned short* __restrict__ Vt, const unsigned short* __restrict__ Em,
    float* __restrict__ out) {
  const int bh = blockIdx.y, b = bh >> 4, h = bh & 15;
  const int q0 = blockIdx.x * 64;
  const int tid = threadIdx.x, w = tid >> 6, lane = tid & 63, g = lane >> 4, cc = lane & 15;
  const size_t bhoff = (size_t)bh * LL * HDIM;

  __shared__ __align__(16) unsigned short Ps[64 * 64];     // P tile, swizzled chunks
  __shared__ __align__(16) unsigned short Ks[2][64 * 64];  // [key][d], swizzled chunks
  __shared__ __align__(16) unsigned short Vs[2][64 * 64];  // [d][pos], swizzled chunks

  // Q fragments straight from global (loop-invariant); wave w owns q rows [w*16, w*16+16)
  bf16x8 aq[2];
#pragma unroll
  for (int ks = 0; ks < 2; ++ks)
    aq[ks] = *reinterpret_cast<const bf16x8*>(
        Qb + bhoff + (size_t)(q0 + w * 16 + cc) * HDIM + ks * 32 + g * 8);

  // async staging: wave w stages K segs {w, w+4} and V segs {w, w+4}
  const int srow = lane >> 3;
  const int gcs = ((lane & 7) - srow) & 7;
  const unsigned short* kg0 = Kb + bhoff + (size_t)(w * 8 + srow) * HDIM + gcs * 8;
  const unsigned short* kg1 = Kb + bhoff + (size_t)(32 + w * 8 + srow) * HDIM + gcs * 8;
  const unsigned short* vg0 = Vt + bhoff + (size_t)(w * 8 + srow) * LL + gcs * 8;
  const unsigned short* vg1 = Vt + bhoff + (size_t)(32 + w * 8 + srow) * LL + gcs * 8;

  float li[4];
  f32x4 oacc[4];
#pragma unroll
  for (int r = 0; r < 4; ++r) li[r] = 0.0f;
#pragma unroll
  for (int nt = 0; nt < 4; ++nt) oacc[nt] = (f32x4)0.0f;

  const unsigned short* embase = Em + ((size_t)b * LL + q0 + w * 16) * LL + 4 * cc;

  // stage tile 0 into buf 0
  async_cp16(kg0, Ks[0] + w * 512);
  async_cp16(kg1, Ks[0] + (w + 4) * 512);
  async_cp16(vg0, Vs[0] + w * 512);
  async_cp16(vg1, Vs[0] + (w + 4) * 512);

#pragma unroll 2
  for (int kt = 0; kt < 32; ++kt) {
    const int buf = kt & 1;
    __syncthreads();  // drains own asyncs -> tile kt ready; prior reads of buf^1 done
    if (kt + 1 < 32) {
      const int nb = buf ^ 1;
      async_cp16(kg0 + (size_t)(kt + 1) * 64 * HDIM, Ks[nb] + w * 512);
      async_cp16(kg1 + (size_t)(kt + 1) * 64 * HDIM, Ks[nb] + (w + 4) * 512);
      async_cp16(vg0 + (kt + 1) * 64, Vs[nb] + w * 512);
      async_cp16(vg1 + (kt + 1) * 64, Vs[nb] + (w + 4) * 512);
    }
    uint2 emv[4];
#pragma unroll
    for (int r = 0; r < 4; ++r)
      emv[r] = *reinterpret_cast<const uint2*>(embase + (size_t)(g * 4 + r) * LL + kt * 64);

    // S = Q @ K^T
    bf16x8 bk_[4][2];
#pragma unroll
    for (int nt = 0; nt < 4; ++nt)
#pragma unroll
      for (int ks = 0; ks < 2; ++ks)
        bk_[nt][ks] = ld_frag(&Ks[buf][(nt * 16 + cc) * 64 + ((4 * ks + g + cc) & 7) * 8]);
    f32x4 sacc[4];
#pragma unroll
    for (int nt = 0; nt < 4; ++nt) sacc[nt] = (f32x4)0.0f;
#pragma unroll
    for (int nt = 0; nt < 4; ++nt)
#pragma unroll
      for (int ks = 0; ks < 2; ++ks)
        sacc[nt] = __builtin_amdgcn_mfma_f32_16x16x32_bf16(aq[ks], bk_[nt][ks], sacc[nt], 0, 0, 0);

    // p = exp2(s) * em; pack 4 bf16 -> one b64 store at swizzled pos
#pragma unroll
    for (int r = 0; r < 4; ++r) {
      unsigned int ex = emv[r].x, ey = emv[r].y;
      float e0 = __builtin_bit_cast(float, ex << 16);
      float e1 = __builtin_bit_cast(float, ex & 0xffff0000u);
      float e2 = __builtin_bit_cast(float, ey << 16);
      float e3 = __builtin_bit_cast(float, ey & 0xffff0000u);
      float p0 = __builtin_amdgcn_exp2f(sacc[0][r]) * e0;
      float p1 = __builtin_amdgcn_exp2f(sacc[1][r]) * e1;
      float p2 = __builtin_amdgcn_exp2f(sacc[2][r]) * e2;
      float p3 = __builtin_amdgcn_exp2f(sacc[3][r]) * e3;
      unsigned int u01 = __builtin_amdgcn_perm(__builtin_bit_cast(unsigned int, p1),
                                               __builtin_bit_cast(unsigned int, p0),
                                               0x07060302u);
      unsigned int u23 = __builtin_amdgcn_perm(__builtin_bit_cast(unsigned int, p3),
                                               __builtin_bit_cast(unsigned int, p2),
                                               0x07060302u);
      li[r] += __builtin_bit_cast(float, u01 << 16) +
               __builtin_bit_cast(float, u01 & 0xffff0000u) +
               __builtin_bit_cast(float, u23 << 16) +
               __builtin_bit_cast(float, u23 & 0xffff0000u);
      uint2 pk; pk.x = u01; pk.y = u23;
      int prow = w * 16 + g * 4 + r;
      int poff = prow * 64 + ((((cc >> 1) + prow) & 7) << 3) + ((cc & 1) << 2);
      *reinterpret_cast<uint2*>(&Ps[poff]) = pk;
    }
    asm volatile("" ::: "memory");  // P stores before same-wave P frag reads

    // O += P @ V  (k-dim = pos, matches Vs column order)
    bf16x8 ap[2], bv[4][2];
    {
      int arow = w * 16 + cc;
#pragma unroll
      for (int ks = 0; ks < 2; ++ks)
        ap[ks] = ld_frag(&Ps[arow * 64 + (((ks * 4 + g + arow) & 7) << 3)]);
    }
#pragma unroll
    for (int nt = 0; nt < 4; ++nt)
#pragma unroll
      for (int ks = 0; ks < 2; ++ks)
        bv[nt][ks] = ld_frag(&Vs[buf][(nt * 16 + cc) * 64 + ((4 * ks + g + cc) & 7) * 8]);
#pragma unroll
    for (int nt = 0; nt < 4; ++nt)
#pragma unroll
      for (int ks = 0; ks < 2; ++ks)
        oacc[nt] = __builtin_amdgcn_mfma_f32_16x16x32_bf16(ap[ks], bv[nt][ks], oacc[nt], 0, 0, 0);
  }

  // epilogue: reduce li over cc-lanes, normalize, write [B, L, H*HD] fp32
#pragma unroll
  for (int r = 0; r < 4; ++r) {
    float s = li[r];
    s += __shfl_xor(s, 1);
    s += __shfl_xor(s, 2);
    s += __shfl_xor(s, 4);
    s += __shfl_xor(s, 8);
    float inv = 1.0f / s;
    int qrow = q0 + w * 16 + g * 4 + r;
#pragma unroll
    for (int nt = 0; nt < 4; ++nt)
      out[((size_t)b * LL + qrow) * 1024 + h * 64 + nt * 16 + cc] = oacc[nt][r] * inv;
  }
}

extern "C" void kernel_launch(void* const* d_in, const int* in_sizes, int n_in,
                              void* d_out, int out_size, void* d_ws, size_t ws_size,
                              hipStream_t stream) {
  const float* x    = (const float*)d_in[0];
  const float* mask = (const float*)d_in[1];
  const float* Wq   = (const float*)d_in[2];
  const float* bq   = (const float*)d_in[3];
  const float* Wk   = (const float*)d_in[4];
  const float* bk   = (const float*)d_in[5];
  const float* Wv   = (const float*)d_in[6];
  const float* bv   = (const float*)d_in[7];
  float* out = (float*)d_out;
  (void)in_sizes; (void)n_in; (void)out_size; (void)ws_size;

  char* ws = (char*)d_ws;
  // qkv @0 (24 MiB); xb @24 (8 MiB); Wt @32 (6 MiB);
  // em @24 (16 MiB) overlaps xb/Wt — dead after qkv_gemm (same-stream serialization),
  // which is why em_prep MUST launch after qkv_gemm.
  unsigned short* qkv = (unsigned short*)(ws);
  unsigned short* xb  = (unsigned short*)(ws + (24u << 20));
  unsigned short* Wt  = (unsigned short*)(ws + (32u << 20));
  unsigned short* em  = (unsigned short*)(ws + (24u << 20));

  prep_kernel<<<dim3(4864), dim3(256), 0, stream>>>(x, Wq, Wk, Wv, xb, Wt);
  qkv_gemm_kernel<<<dim3(8, 32, 3), dim3(256), 0, stream>>>(xb, Wt, bq, bk, bv, qkv);
  em_prep_kernel<<<dim3(2, 4096), dim3(256), 0, stream>>>(mask, em);
  flash_kernel<<<dim3(32, 32), dim3(256), 0, stream>>>(qkv, qkv + 4194304, qkv + 8388608,
                                                       em, out);
}